// Round 1
// 12454.907 us; speedup vs baseline: 1.0907x; 1.0907x over previous
//
#include <hip/hip_runtime.h>
#include <cstdint>
#include <cstddef>

// FC_LSTM on MI355X — Round 5: CU-resident weights (VGPR cache + LDS Wco).
// R4 evidence: scan 13.06ms = 15.3K cyc/step; 896 KB weights streamed from L2
// per CU per step at ~64 B/cyc (per-CU L2-return port ~94% saturated).
// Fix: 512 threads/block (8 waves -> 256-VGPR budget), each thread owns rows
// (t, t+512): register-cache 14/32 Wh chunks per row + 8/32 Wp chunks
// (136 VGPRs of weights); Wco fully LDS-resident (128 KB, off the vmem port).
// Streamed bytes/step: 896 KB -> 480 KB. fdot2 order preserved exactly vs R4
// (bit-identical outputs expected).

typedef unsigned short u16;
typedef unsigned int   u32;
typedef float  v4f __attribute__((ext_vector_type(4)));
typedef short  v8s __attribute__((ext_vector_type(8)));
typedef _Float16 h2 __attribute__((ext_vector_type(2)));

#define SEQ 2048
#define NB  32
#define HID 256
#define G4  1024
#define FIN 128
#define COFF (2049*NB*HID)   // element offset of memorys half of d_out

// uint4-unit offsets in ws
#define WH4_OFF  0        // [32][1024] : chunk kc (k=8kc..8kc+7), row n
#define WP4_OFF  32768    // [32][512]  : rows = [Wci n | Wcf n+256]
#define WCO4_OFF 49152    // [32][256]
#define WX4_OFF  57344    // [16][1024] (fallback path)
#define W4_TOTAL 73728    // uint4 count (1.125 MB)

// register-cache depth (uint4 chunks = 8 f16 each)
#define CWH 14   // cached Wh chunks per row (of 32)
#define CWP 8    // cached Wp chunks per row (of 32)

__device__ __forceinline__ u16 f2bf(float f) {
  u32 u = __builtin_bit_cast(u32, f);
  u32 r = (u + 0x7fffu + ((u >> 16) & 1u)) >> 16;
  return (u16)r;
}
__device__ __forceinline__ u16 f2h_bits(float f) {
  _Float16 h = (_Float16)f;
  return __builtin_bit_cast(u16, h);
}
__device__ __forceinline__ u32 pack2f(float a, float b) {
  u32 lo = f2h_bits(a);
  u32 hi = f2h_bits(b);
  return lo | (hi << 16);
}
__device__ __forceinline__ float fd(u32 w, u32 u, float acc) {
  h2 hw = __builtin_bit_cast(h2, w);
  h2 hu = __builtin_bit_cast(h2, u);
  return __builtin_amdgcn_fdot2(hw, hu, acc, false);
}
__device__ __forceinline__ float sigm(float v) { return 1.f / (1.f + __expf(-v)); }
__device__ __forceinline__ float tanh_fast(float x) {
  float xx = fminf(fmaxf(x, -15.f), 15.f);
  float e = __expf(2.f * xx);
  return (e - 1.f) / (e + 1.f);
}

// ---------------- Phase 0: weight repack (f32 -> f16 x8 chunks) -------------
__global__ __launch_bounds__(256) void prep_weights(
    const float* __restrict__ Wh, const float* __restrict__ Wci,
    const float* __restrict__ Wcf, const float* __restrict__ Wco,
    const float* __restrict__ Wx, uint4* __restrict__ ws4)
{
  int i = blockIdx.x * 256 + threadIdx.x;
  if (i >= W4_TOTAL) return;
  const float* src;
  if (i < WP4_OFF) {                       // WhT4
    int kc = i >> 10, n = i & 1023;
    src = Wh + n*256 + kc*8;
  } else if (i < WCO4_OFF) {               // WpT4
    int l = i - WP4_OFF; int kc = l >> 9, n = l & 511;
    src = ((n < 256) ? (Wci + n*256) : (Wcf + (n-256)*256)) + kc*8;
  } else if (i < WX4_OFF) {                // WcoT4
    int l = i - WCO4_OFF; int kc = l >> 8, n = l & 255;
    src = Wco + n*256 + kc*8;
  } else {                                 // WxT4 (fallback)
    int l = i - WX4_OFF; int kc = l >> 10, n = l & 1023;
    src = Wx + n*128 + kc*8;
  }
  uint4 r;
  r.x = pack2f(src[0], src[1]);
  r.y = pack2f(src[2], src[3]);
  r.z = pack2f(src[4], src[5]);
  r.w = pack2f(src[6], src[7]);
  ws4[i] = r;
}

// ---------------- Phase 1: xw GEMM (bf16 MFMA, f32 inputs) ------------------
__global__ __launch_bounds__(256) void xw_gemm(
    const float* __restrict__ x, const float* __restrict__ Wx,
    const float* __restrict__ bx, const float* __restrict__ bh,
    u16* __restrict__ xw)
{
  int wave = threadIdx.x >> 6, lane = threadIdx.x & 63;
  int s = lane & 15, q = lane >> 4;
  int mtile = blockIdx.x;              // 0..4095
  int ntile = blockIdx.y * 4 + wave;   // 0..63
  const float* xa = x  + (size_t)(mtile*16 + s) * 128 + q*8;
  const float* wb = Wx + (size_t)(ntile*16 + s) * 128 + q*8;
  v4f acc = {0.f, 0.f, 0.f, 0.f};
#pragma unroll
  for (int ko = 0; ko < 4; ++ko) {
    float4 a0 = *reinterpret_cast<const float4*>(xa + ko*32);
    float4 a1 = *reinterpret_cast<const float4*>(xa + ko*32 + 4);
    float4 b0 = *reinterpret_cast<const float4*>(wb + ko*32);
    float4 b1 = *reinterpret_cast<const float4*>(wb + ko*32 + 4);
    v8s a, b;
    a[0]=(short)f2bf(a0.x); a[1]=(short)f2bf(a0.y); a[2]=(short)f2bf(a0.z); a[3]=(short)f2bf(a0.w);
    a[4]=(short)f2bf(a1.x); a[5]=(short)f2bf(a1.y); a[6]=(short)f2bf(a1.z); a[7]=(short)f2bf(a1.w);
    b[0]=(short)f2bf(b0.x); b[1]=(short)f2bf(b0.y); b[2]=(short)f2bf(b0.z); b[3]=(short)f2bf(b0.w);
    b[4]=(short)f2bf(b1.x); b[5]=(short)f2bf(b1.y); b[6]=(short)f2bf(b1.z); b[7]=(short)f2bf(b1.w);
    acc = __builtin_amdgcn_mfma_f32_16x16x32_bf16(a, b, acc, 0, 0, 0);
  }
  int n = ntile*16 + s;
  float bias = bx[n] + bh[n];
#pragma unroll
  for (int p = 0; p < 4; ++p) {
    int m = mtile*16 + q*4 + p;
    int bb = m >> 11, t = m & 2047;   // r = b*2048 + t
    xw[(size_t)(t*NB + bb) * G4 + n] = f2h_bits(acc[p] + bias);
  }
}

// ---------------- Phase 2: recurrent scan -----------------------------------
// 512 threads: thread t owns output rows n0 = t and n1 = 512 + t.
// n0 in [0,512) -> gates i (t<256) / f (t>=256), which take the Wp peephole.
// n1 in [512,1024) -> gates o (t<256) / g (t>=256).
template<bool PRE>
__global__ __launch_bounds__(512, 2) void lstm_scan(
    const uint4* __restrict__ ws4, const void* __restrict__ xsrc_v,
    const float* __restrict__ bx, const float* __restrict__ bh,
    const float* __restrict__ bci, const float* __restrict__ bcf,
    const float* __restrict__ bco, float* __restrict__ out)
{
  const int b = blockIdx.x, t = threadIdx.x;   // t in [0,512)
  const uint4* WhT4  = ws4 + WH4_OFF;
  const uint4* WpT4  = ws4 + WP4_OFF;
  const uint4* WcoT4 = ws4 + WCO4_OFF;
  const uint4* WxT4  = ws4 + WX4_OFF;

  // Wco fully LDS-resident: 32*256 uint4 = 128 KB (reads leave the vmem port)
  __shared__ __align__(16) uint4 s_wco[8192];

  __shared__ __align__(16) float s_i[256], s_f[256], s_g[256], s_op[256];
  __shared__ __align__(16) float s_c[256], s_cn[256], s_z[4][256];
  __shared__ __align__(16) u16 s_hh[256];   // f16 bits of h
  __shared__ __align__(16) u16 s_cc[256];   // f16 bits of c (and c_new)
  __shared__ __align__(16) u16 s_x[128];    // f16 bits of x row (fallback only)
  __shared__ float s_bci[256], s_bcf[256], s_bco[256];

  for (int i = t; i < 8192; i += 512) s_wco[i] = WcoT4[i];

  if (t < 256) {
    s_c[t] = 0.f; s_hh[t] = 0; s_cc[t] = 0;
    s_bci[t] = bci[t];
    s_bcf[t] = bcf[t];
    s_bco[t] = bco[t];
    out[b*HID + t] = 0.f;          // h0 = 0
    out[COFF + b*HID + t] = 0.f;   // c0 = 0
  }

  const int n1 = 512 + t;
  float biasA = 0.f, biasB = 0.f;
  if (!PRE) { biasA = bx[t] + bh[t]; biasB = bx[n1] + bh[n1]; }

  // register-resident weight chunks (compile-time indexed -> VGPRs, rule #20)
  uint4 whA[CWH], whB[CWH], wpA[CWP];
#pragma unroll
  for (int kc = 0; kc < CWH; ++kc) {
    whA[kc] = WhT4[kc*1024 + t];
    whB[kc] = WhT4[kc*1024 + n1];
  }
#pragma unroll
  for (int kc = 0; kc < CWP; ++kc) wpA[kc] = WpT4[kc*512 + t];

  __syncthreads();

  const u16* xw = (const u16*)xsrc_v;

  for (int ts = 0; ts < SEQ; ++ts) {
    u16 xw0 = 0, xw1 = 0;
    if (PRE) {
      // prefetch early; consumed after the dot loops (latency hidden)
      const u16* xr = xw + (size_t)(ts*NB + b) * G4;
      xw0 = xr[t]; xw1 = xr[n1];
    } else {
      if (t < 128) {
        const float* xr2 = (const float*)xsrc_v + (size_t)(b*SEQ + ts) * FIN;
        s_x[t] = f2h_bits(xr2[t]);
      }
      __syncthreads();
    }

    float a0 = 0.f, a1 = 0.f, c0 = 0.f, c1 = 0.f;
    // Wh, cached chunks (kc 0..CWH), then streamed (kc CWH..32) — same
    // ascending-kc, even/odd-word accumulation order as R4.
#pragma unroll
    for (int kc = 0; kc < CWH; ++kc) {
      uint4 hh = *reinterpret_cast<const uint4*>(&s_hh[8*kc]);
      a0 = fd(whA[kc].x, hh.x, a0); a1 = fd(whA[kc].y, hh.y, a1);
      a0 = fd(whA[kc].z, hh.z, a0); a1 = fd(whA[kc].w, hh.w, a1);
      c0 = fd(whB[kc].x, hh.x, c0); c1 = fd(whB[kc].y, hh.y, c1);
      c0 = fd(whB[kc].z, hh.z, c0); c1 = fd(whB[kc].w, hh.w, c1);
    }
#pragma unroll 4
    for (int kc = CWH; kc < 32; ++kc) {
      uint4 wA = WhT4[kc*1024 + t];
      uint4 wB = WhT4[kc*1024 + n1];
      uint4 hh = *reinterpret_cast<const uint4*>(&s_hh[8*kc]);
      a0 = fd(wA.x, hh.x, a0); a1 = fd(wA.y, hh.y, a1);
      a0 = fd(wA.z, hh.z, a0); a1 = fd(wA.w, hh.w, a1);
      c0 = fd(wB.x, hh.x, c0); c1 = fd(wB.y, hh.y, c1);
      c0 = fd(wB.z, hh.z, c0); c1 = fd(wB.w, hh.w, c1);
    }
    if (!PRE) {
#pragma unroll 4
      for (int kc = 0; kc < 16; ++kc) {
        uint4 wA = WxT4[kc*1024 + t];
        uint4 wB = WxT4[kc*1024 + n1];
        uint4 xx = *reinterpret_cast<const uint4*>(&s_x[8*kc]);
        a0 = fd(wA.x, xx.x, a0); a1 = fd(wA.y, xx.y, a1);
        a0 = fd(wA.z, xx.z, a0); a1 = fd(wA.w, xx.w, a1);
        c0 = fd(wB.x, xx.x, c0); c1 = fd(wB.y, xx.y, c1);
        c0 = fd(wB.z, xx.z, c0); c1 = fd(wB.w, xx.w, c1);
      }
    }
    // Wp peephole for n0 (rows 0..512 == n0 exactly; now all threads, no
    // divergence). Cached then streamed, ascending kc.
#pragma unroll
    for (int kc = 0; kc < CWP; ++kc) {
      uint4 cc = *reinterpret_cast<const uint4*>(&s_cc[8*kc]);
      a0 = fd(wpA[kc].x, cc.x, a0); a1 = fd(wpA[kc].y, cc.y, a1);
      a0 = fd(wpA[kc].z, cc.z, a0); a1 = fd(wpA[kc].w, cc.w, a1);
    }
#pragma unroll 4
    for (int kc = CWP; kc < 32; ++kc) {
      uint4 w  = WpT4[kc*512 + t];
      uint4 cc = *reinterpret_cast<const uint4*>(&s_cc[8*kc]);
      a0 = fd(w.x, cc.x, a0); a1 = fd(w.y, cc.y, a1);
      a0 = fd(w.z, cc.z, a0); a1 = fd(w.w, cc.w, a1);
    }

    float accA = a0 + a1;
    float accB = c0 + c1;
    if (PRE) {
      accA += (float)__builtin_bit_cast(_Float16, xw0);
      accB += (float)__builtin_bit_cast(_Float16, xw1);
    } else {
      accA += biasA;
      accB += biasB;
    }

    int idx = t & 255;
    if (t < 256) { s_i[idx]  = sigm(accA + s_bci[idx]); s_op[idx] = accB; }
    else         { s_f[idx]  = sigm(accA + s_bcf[idx]); s_g[idx]  = tanh_fast(accB); }
    __syncthreads();

    if (t < 256) {
      float cn = s_f[t]*s_c[t] + s_i[t]*s_g[t];
      s_cn[t] = cn; s_c[t] = cn;
      s_cc[t] = f2h_bits(cn);
      out[COFF + (size_t)(ts+1)*(NB*HID) + b*HID + t] = cn;
    }
    __syncthreads();

    {   // o-peephole: z = Wco . c_new from LDS. Same 4-way K split as R4:
        // thread t covers parts p0 = t>>8 (0/1) and p0+2, nn = t&255.
      int nn = t & 255, p0 = t >> 8;
      float z0 = 0.f, z1 = 0.f, z2 = 0.f, z3 = 0.f;
#pragma unroll
      for (int j = 0; j < 8; ++j) {
        int kc = p0*8 + j;
        uint4 w  = s_wco[kc*256 + nn];
        uint4 cc = *reinterpret_cast<const uint4*>(&s_cc[8*kc]);
        z0 = fd(w.x, cc.x, z0); z1 = fd(w.y, cc.y, z1);
        z0 = fd(w.z, cc.z, z0); z1 = fd(w.w, cc.w, z1);
      }
#pragma unroll
      for (int j = 0; j < 8; ++j) {
        int kc = (p0+2)*8 + j;
        uint4 w  = s_wco[kc*256 + nn];
        uint4 cc = *reinterpret_cast<const uint4*>(&s_cc[8*kc]);
        z2 = fd(w.x, cc.x, z2); z3 = fd(w.y, cc.y, z3);
        z2 = fd(w.z, cc.z, z2); z3 = fd(w.w, cc.w, z3);
      }
      s_z[p0][nn]   = z0 + z1;
      s_z[p0+2][nn] = z2 + z3;
    }
    __syncthreads();

    if (t < 256) {
      float z = s_z[0][t] + s_z[1][t] + s_z[2][t] + s_z[3][t]
              + s_op[t] + s_bco[t];
      float o  = sigm(z);
      float hn = o * tanh_fast(s_cn[t]);
      out[(size_t)(ts+1)*(NB*HID) + b*HID + t] = hn;
      s_hh[t] = f2h_bits(hn);       // h for next step
    }
    __syncthreads();
  }
}

// ---------------- launch ----------------------------------------------------
extern "C" void kernel_launch(void* const* d_in, const int* in_sizes, int n_in,
                              void* d_out, int out_size, void* d_ws, size_t ws_size,
                              hipStream_t stream)
{
  const float* x   = (const float*)d_in[0];
  const float* Wx  = (const float*)d_in[1];
  const float* bx  = (const float*)d_in[2];
  const float* Wh  = (const float*)d_in[3];
  const float* bh  = (const float*)d_in[4];
  const float* Wci = (const float*)d_in[5];
  const float* bci = (const float*)d_in[6];
  const float* Wcf = (const float*)d_in[7];
  const float* bcf = (const float*)d_in[8];
  const float* Wco = (const float*)d_in[9];
  const float* bco = (const float*)d_in[10];
  float* out = (float*)d_out;
  uint4* ws4 = (uint4*)d_ws;
  u16* xw  = (u16*)((char*)d_ws + (size_t)W4_TOTAL*16);

  const size_t NEED = (size_t)W4_TOTAL*16 + (size_t)SEQ*NB*G4*2;  // ~129 MB
  const bool pre = (ws_size >= NEED);   // constant across calls -> capture-safe

  hipLaunchKernelGGL(prep_weights, dim3((W4_TOTAL + 255)/256), dim3(256), 0, stream,
                     Wh, Wci, Wcf, Wco, Wx, ws4);
  if (pre) {
    hipLaunchKernelGGL(xw_gemm, dim3(4096, 16), dim3(256), 0, stream,
                       x, Wx, bx, bh, xw);
    hipLaunchKernelGGL((lstm_scan<true>), dim3(32), dim3(512), 0, stream,
                       ws4, (const void*)xw, bx, bh, bci, bcf, bco, out);
  } else {
    hipLaunchKernelGGL((lstm_scan<false>), dim3(32), dim3(512), 0, stream,
                       ws4, (const void*)x, bx, bh, bci, bcf, bco, out);
  }
}